// Round 1
// baseline (232.427 us; speedup 1.0000x reference)
//
#include <hip/hip_runtime.h>

// DynamiConv: out[b,o,i,j] = gate[b,i,j] * conv3x3(x,W)[b,o,i,j] + bias[o]
//             gate[b,i,j]  = conv3x3(sigmoid(x), dW)[b,0,i,j]
// Shapes: x[8,32,256,256] f32, W[32,32,3,3], dW[1,32,3,3], bias[32]; out[8,32,256,256]

#define BATCH 8
#define CIN   32
#define COUT  32
#define HH    256
#define WW    256
#define KF    288          // CIN*9, unfold feature dim, f = c*9 + ki*3 + kj
#define TW    64           // spatial tile width
#define TH    8            // spatial tile height
#define CCH   4            // channels staged per chunk
#define NCHUNK (CIN/CCH)
#define HTW   (TW+2)       // 66 (halo)
#define HTH   (TH+2)       // 10 (halo)
#define LDS_ELEMS (CCH*HTH*HTW)   // 2640

// Transpose weight [O][KF] -> wT [KF][O] so the per-f weight row is 32
// contiguous floats at a wave-uniform address (compiler emits s_load_dwordx16).
__global__ __launch_bounds__(256) void prep_wT(const float* __restrict__ w,
                                               float* __restrict__ wT) {
  int t = blockIdx.x * 256 + threadIdx.x;
  if (t < COUT * KF) {
    int o = t & (COUT - 1);
    int f = t >> 5;
    wT[f * COUT + o] = w[o * KF + f];
  }
}

__global__ __launch_bounds__(256, 4) void dynconv(
    const float* __restrict__ x, const float* __restrict__ wT,
    const float* __restrict__ dw, const float* __restrict__ bias,
    float* __restrict__ out) {
  __shared__ float lv[LDS_ELEMS];   // raw x tile (zero-padded halo)
  __shared__ float ls[LDS_ELEMS];   // sigmoid(x) tile (pad -> sigmoid(0)=0.5, matches ref)

  const int bid = blockIdx.x;            // grid = 8 * 32 * 4 = 1024
  const int bw  = bid & 3;               // WW/TW = 4
  const int bh  = (bid >> 2) & 31;       // HH/TH = 32
  const int b   = bid >> 7;
  const int x0  = bw * TW;
  const int y0  = bh * TH;
  const int tid = threadIdx.x;
  const int tx  = tid & 63;              // col within tile
  const int ty  = tid >> 6;              // 0..3; this thread owns rows ty*2, ty*2+1

  float acc0[COUT], acc1[COUT];
  float g0 = 0.f, g1 = 0.f;
#pragma unroll
  for (int o = 0; o < COUT; ++o) { acc0[o] = 0.f; acc1[o] = 0.f; }

  for (int ch = 0; ch < NCHUNK; ++ch) {
    const int c0 = ch * CCH;
    __syncthreads();   // previous chunk's compute done before overwrite
    // ---- stage chunk: coalesced rows of 66, sigmoid computed once per element ----
    for (int i = tid; i < LDS_ELEMS; i += 256) {
      const int col = i % HTW;
      const int t2  = i / HTW;
      const int row = t2 % HTH;
      const int cc  = t2 / HTH;
      const int gx = x0 + col - 1;
      const int gy = y0 + row - 1;
      float v = 0.f;
      if (gx >= 0 && gx < WW && gy >= 0 && gy < HH)
        v = x[(((size_t)(b * CIN + c0 + cc) * HH + gy) * WW) + gx];
      lv[i] = v;
      ls[i] = 1.0f / (1.0f + __expf(-v));
    }
    __syncthreads();

    // ---- compute: 36 f-values per chunk ----
    for (int cc = 0; cc < CCH; ++cc) {
#pragma unroll
      for (int ki = 0; ki < 3; ++ki) {
#pragma unroll
        for (int kj = 0; kj < 3; ++kj) {
          const int f = (c0 + cc) * 9 + ki * 3 + kj;
          const float* __restrict__ wrow = wT + f * COUT;  // uniform -> s_load
          const float dwf = dw[f];                          // uniform -> s_load
          const int i0 = (cc * HTH + ty * 2 + ki) * HTW + tx + kj;
          const int i1 = i0 + HTW;
          const float v0 = lv[i0];
          const float v1 = lv[i1];
          g0 += dwf * ls[i0];
          g1 += dwf * ls[i1];
#pragma unroll
          for (int o = 0; o < COUT; ++o) {
            const float wv = wrow[o];
            acc0[o] += wv * v0;
            acc1[o] += wv * v1;
          }
        }
      }
    }
  }

  // ---- epilogue: out = acc*gate + bias, coalesced 64-lane rows ----
  const int gy0 = y0 + ty * 2;
#pragma unroll
  for (int o = 0; o < COUT; ++o) {
    const float bo = bias[o];
    const size_t base = ((size_t)(b * COUT + o) * HH + gy0) * WW + x0 + tx;
    out[base]      = acc0[o] * g0 + bo;
    out[base + WW] = acc1[o] * g1 + bo;
  }
}

extern "C" void kernel_launch(void* const* d_in, const int* in_sizes, int n_in,
                              void* d_out, int out_size, void* d_ws, size_t ws_size,
                              hipStream_t stream) {
  const float* x    = (const float*)d_in[0];
  const float* w    = (const float*)d_in[1];
  const float* dw   = (const float*)d_in[2];   // already f-major: c*9+ki*3+kj
  const float* bias = (const float*)d_in[3];
  float* out = (float*)d_out;
  float* wT  = (float*)d_ws;                   // 9216 floats = 36 KB scratch

  prep_wT<<<(COUT * KF + 255) / 256, 256, 0, stream>>>(w, wT);
  dynconv<<<BATCH * (HH / TH) * (WW / TW), 256, 0, stream>>>(x, wT, dw, bias, out);
}

// Round 2
// 168.649 us; speedup vs baseline: 1.3782x; 1.3782x over previous
//
#include <hip/hip_runtime.h>

// DynamiConv via implicit-im2col f16 MFMA:
//   out[b,o,y,x] = gate[b,y,x] * (W[o,:] . cols[:,b,y,x]) + bias[o]
//   gate = dW . sigmoid(cols)  (scalar per position, fused in-register)
// x[8,32,256,256] f32, W[32,32,3,3], dW[1,32,3,3], bias[32] -> out[8,32,256,256] f32

typedef _Float16 half8 __attribute__((ext_vector_type(8)));
typedef float f32x4 __attribute__((ext_vector_type(4)));
typedef float f32x16 __attribute__((ext_vector_type(16)));

#define BATCH 8
#define CIN 32
#define COUT 32
#define HH 256
#define WW 256
#define TW 32            // spatial tile width  (= one MFMA n-tile row)
#define TH 16            // spatial tile height (16 n-tiles, 4 per wave)
#define HTW 34           // +2 halo
#define HTH 18
#define CSTR 40          // f16 per position in LDS (32 ch + 8 pad) = 80 B, 16B-aligned
#define NCHUNK 18        // K = 288 = 18 chunks of 16 (chunk q: tap=q>>1, c-half=q&1)

// Pack A-fragments (f16, per-lane order) and dW coefs (f32) into d_ws.
// Apack[q][lane][j]: o=lane&31, k=(lane>>5)*8+j, c=(q&1)*16+k, tap=q>>1
__global__ __launch_bounds__(256) void prep_pack(const float* __restrict__ w,
                                                 const float* __restrict__ dw,
                                                 _Float16* __restrict__ Apack,
                                                 float* __restrict__ dwpack) {
  int t = blockIdx.x * 256 + threadIdx.x;
  if (t < NCHUNK * 64 * 8) {
    int q = t >> 9, lane = (t >> 3) & 63, j = t & 7;
    int tap = q >> 1, h = q & 1;
    int o = lane & 31, lh = lane >> 5;
    int c = h * 16 + lh * 8 + j;
    Apack[t] = (_Float16)w[o * 288 + c * 9 + tap];   // W[o][c][ki][kj], tap=ki*3+kj
  } else if (t < NCHUNK * 64 * 8 + NCHUNK * 16) {
    int i = t - NCHUNK * 64 * 8;
    int q = i >> 4, k = i & 15;
    int tap = q >> 1, h = q & 1;
    dwpack[i] = dw[(h * 16 + k) * 9 + tap];
  }
}

__global__ __launch_bounds__(256, 3) void dynconv(
    const float* __restrict__ x, const _Float16* __restrict__ Apack,
    const float* __restrict__ dwpack, const float* __restrict__ bias,
    float* __restrict__ out) {
  __shared__ __align__(16) _Float16 lds[HTH * HTW * CSTR];   // 48960 B

  const int bid = blockIdx.x;              // 8 xt * 16 yt * 8 b = 1024
  const int xt = bid & 7, yt = (bid >> 3) & 15, bb = bid >> 7;
  const int x0 = xt * TW, y0 = yt * TH;
  const int tid = threadIdx.x;

  // ---- stage x tile -> LDS f16, layout [y][x][c], zero-padded halo ----
  // core: 576 (c,y)-rows x 8 float4 (x0..x0+31), 18 iters exactly
  for (int it = 0; it < 18; ++it) {
    int idx = it * 256 + tid;
    int seg = idx & 7, row = idx >> 3;     // row < 576
    int y = row % 18, c = row / 18;
    int gy = y0 + y - 1;
    f32x4 v = {0.f, 0.f, 0.f, 0.f};
    if ((unsigned)gy < 256u)
      v = *(const f32x4*)(x + ((bb * CIN + c) << 16) + (gy << 8) + x0 + seg * 4);
    int p0 = (y * HTW + seg * 4 + 1) * CSTR + c;
#pragma unroll
    for (int u = 0; u < 4; ++u) lds[p0 + u * CSTR] = (_Float16)v[u];
  }
  // halo columns x_l = 0 and 33
  for (int idx = tid; idx < 1152; idx += 256) {
    int side = idx & 1, row = idx >> 1;
    int y = row % 18, c = row / 18;
    int gy = y0 + y - 1;
    int gx = side ? (x0 + 32) : (x0 - 1);
    float v = 0.f;
    if ((unsigned)gy < 256u && (unsigned)gx < 256u)
      v = x[((bb * CIN + c) << 16) + (gy << 8) + gx];
    lds[(y * HTW + (side ? 33 : 0)) * CSTR + c] = (_Float16)v;
  }
  __syncthreads();

  const int lane = tid & 63, w = tid >> 6;
  const int ln = lane & 31, lh = lane >> 5;

  f32x16 acc[4];
  float g[4] = {0.f, 0.f, 0.f, 0.f};
#pragma unroll
  for (int r = 0; r < 4; ++r)
#pragma unroll
    for (int i = 0; i < 16; ++i) acc[r][i] = 0.f;

  for (int q = 0; q < NCHUNK; ++q) {
    const int tap = q >> 1, h = q & 1;
    const int ki = tap / 3, kj = tap - ki * 3;
    const half8 a = *(const half8*)(Apack + ((q * 64 + lane) << 3));   // 16B/lane
    const f32x4 dwa = *(const f32x4*)(dwpack + q * 16 + lh * 8);
    const f32x4 dwb = *(const f32x4*)(dwpack + q * 16 + lh * 8 + 4);
    const int cof = h * 16 + lh * 8;
#pragma unroll
    for (int r = 0; r < 4; ++r) {
      const int yl = w * 4 + r + ki;        // 0..17
      const int xl = ln + kj;               // 0..33
      const half8 bv = *(const half8*)(lds + (yl * HTW + xl) * CSTR + cof);  // ds_read_b128
      // fused gate: g += dW[c] * sigmoid(v) on this lane's 8 channels
#pragma unroll
      for (int j = 0; j < 8; ++j) {
        float v = (float)bv[j];
        float s = __builtin_amdgcn_rcpf(1.f + __expf(-v));
        g[r] += (j < 4 ? dwa[j] : dwb[j - 4]) * s;
      }
      acc[r] = __builtin_amdgcn_mfma_f32_32x32x16_f16(a, bv, acc[r], 0, 0, 0);
    }
  }

  // ---- epilogue: D layout col=lane&31, row=(reg&3)+8*(reg>>2)+4*(lane>>5) ----
  float bo[16];
#pragma unroll
  for (int reg = 0; reg < 16; ++reg)
    bo[reg] = bias[(reg & 3) + 8 * (reg >> 2) + 4 * lh];
#pragma unroll
  for (int r = 0; r < 4; ++r) {
    float gr = g[r] + __shfl_xor(g[r], 32);   // other half-wave's 16 channels
    const int y = y0 + w * 4 + r;
#pragma unroll
    for (int reg = 0; reg < 16; ++reg) {
      const int o = (reg & 3) + 8 * (reg >> 2) + 4 * lh;
      out[((bb * COUT + o) << 16) + (y << 8) + x0 + ln] = acc[r][reg] * gr + bo[reg];
    }
  }
}

extern "C" void kernel_launch(void* const* d_in, const int* in_sizes, int n_in,
                              void* d_out, int out_size, void* d_ws, size_t ws_size,
                              hipStream_t stream) {
  const float* x    = (const float*)d_in[0];
  const float* wgt  = (const float*)d_in[1];
  const float* dw   = (const float*)d_in[2];
  const float* bias = (const float*)d_in[3];
  float* out = (float*)d_out;

  _Float16* Apack = (_Float16*)d_ws;                         // 9216 f16 = 18432 B
  float* dwpack   = (float*)((char*)d_ws + NCHUNK * 64 * 8 * 2);  // 288 f32

  prep_pack<<<(NCHUNK * 64 * 8 + NCHUNK * 16 + 255) / 256, 256, 0, stream>>>(
      wgt, dw, Apack, dwpack);
  dynconv<<<BATCH * (HH / TH) * (WW / TW), 256, 0, stream>>>(x, Apack, dwpack, bias, out);
}

// Round 3
// 144.436 us; speedup vs baseline: 1.6092x; 1.1676x over previous
//
#include <hip/hip_runtime.h>

// DynamiConv via implicit-im2col f16 MFMA, gate fused as a second MFMA:
//   out[b,o,y,x] = gate[b,y,x] * (W . cols)[o] + bias[o]
//   gate = dW . sigmoid(cols), computed by MFMA with dW replicated in all 32 A-rows
//   -> gate accumulator is position-aligned with the main accumulator (col=lane&31).
// x[8,32,256,256] f32, W[32,32,3,3], dW[1,32,3,3], bias[32] -> out[8,32,256,256] f32

typedef _Float16 half8 __attribute__((ext_vector_type(8)));
typedef _Float16 half4 __attribute__((ext_vector_type(4)));
typedef float f32x16 __attribute__((ext_vector_type(16)));

#define BATCH 8
#define CIN 32
#define COUT 32
#define HH 256
#define WW 256
#define TW 32           // spatial tile width (one MFMA n-tile)
#define TH 8            // spatial tile height (8 n-rows, 1 per wave, 512 thr)
#define HTW 34
#define HTH 10
#define CSTR 40         // f16 per position (32 ch + 8 pad) = 80 B stride, 16B-aligned frags
#define NCHUNK 18       // K=288 as 18 chunks of 16: chunk q -> tap=q>>1, c-half=q&1
#define NPOS (HTH*HTW)  // 340 halo positions
#define NITEM (NPOS*8)  // 2720 staging items (4 channels each)

// Pack A fragments: Apack = W in per-lane MFMA A order; Adw = dW replicated over
// all 32 output rows (o-independent). lane: o=lane&31, lh=lane>>5; k-elem j:
// c = (q&1)*16 + lh*8 + j, tap = q>>1 (f-order is tap-major, channel-minor).
__global__ __launch_bounds__(256) void prep_pack(const float* __restrict__ w,
                                                 const float* __restrict__ dw,
                                                 _Float16* __restrict__ Apack,
                                                 _Float16* __restrict__ Adw) {
  int t = blockIdx.x * 256 + threadIdx.x;
  int tt = t < 9216 ? t : t - 9216;
  int q = tt >> 9, lane = (tt >> 3) & 63, j = tt & 7;
  int tap = q >> 1, h = q & 1;
  int o = lane & 31, lh = lane >> 5;
  int c = h * 16 + lh * 8 + j;
  if (t < 9216)
    Apack[t] = (_Float16)w[o * 288 + c * 9 + tap];
  else if (t < 18432)
    Adw[tt] = (_Float16)dw[c * 9 + tap];
}

__global__ __launch_bounds__(512, 4) void dynconv(
    const float* __restrict__ x, const _Float16* __restrict__ Apack,
    const _Float16* __restrict__ Adw, const float* __restrict__ bias,
    float* __restrict__ out) {
  __shared__ __align__(16) _Float16 lv[NPOS * CSTR];   // 27200 B raw values
  __shared__ __align__(16) _Float16 ls[NPOS * CSTR];   // 27200 B sigmoid values

  const int bid = blockIdx.x;                 // 8 xt * 32 yt * 8 b = 2048
  const int xt = bid & 7, yt = (bid >> 3) & 31, bb = bid >> 8;
  const int x0 = xt * TW, y0 = yt * TH;
  const int tid = threadIdx.x;

  // ---- stage: v + sigmoid(v) -> LDS f16, layout [pos][c], ds_write_b64 ----
  for (int i = tid; i < NITEM; i += 512) {
    const int cg = i / NPOS;                  // channel group 0..7 (4 ch)
    const int pos = i - cg * NPOS;
    const int yy = pos / HTW;
    const int xx = pos - yy * HTW;
    const int gy = y0 + yy - 1, gx = x0 + xx - 1;
    float v0 = 0.f, v1 = 0.f, v2 = 0.f, v3 = 0.f;
    if ((unsigned)gy < 256u && (unsigned)gx < 256u) {
      const float* xp = x + (((size_t)(bb * CIN + cg * 4)) << 16) + (gy << 8) + gx;
      v0 = xp[0]; v1 = xp[1 << 16]; v2 = xp[2 << 16]; v3 = xp[3 << 16];
    }
    const float s0 = __builtin_amdgcn_rcpf(1.f + __expf(-v0));
    const float s1 = __builtin_amdgcn_rcpf(1.f + __expf(-v1));
    const float s2 = __builtin_amdgcn_rcpf(1.f + __expf(-v2));
    const float s3 = __builtin_amdgcn_rcpf(1.f + __expf(-v3));
    half4 hv = {(_Float16)v0, (_Float16)v1, (_Float16)v2, (_Float16)v3};
    half4 hs = {(_Float16)s0, (_Float16)s1, (_Float16)s2, (_Float16)s3};
    *(half4*)(lv + pos * CSTR + cg * 4) = hv;
    *(half4*)(ls + pos * CSTR + cg * 4) = hs;
  }
  __syncthreads();

  // ---- compute: wave w8 owns tile row y0+w8; 18 chunks, 2 MFMA each ----
  const int lane = tid & 63, w8 = tid >> 6;
  const int ln = lane & 31, lh = lane >> 5;

  f32x16 acc, accg;
#pragma unroll
  for (int i = 0; i < 16; ++i) { acc[i] = 0.f; accg[i] = 0.f; }

#pragma unroll
  for (int q = 0; q < NCHUNK; ++q) {
    const int tap = q >> 1, h = q & 1;
    const int ki = tap / 3, kj = tap - ki * 3;
    const half8 a  = *(const half8*)(Apack + ((q * 64 + lane) << 3));  // L1-hot
    const half8 ad = *(const half8*)(Adw   + ((q * 64 + lane) << 3));
    const int off = ((w8 + ki) * HTW + ln + kj) * CSTR + h * 16 + lh * 8;
    const half8 bv = *(const half8*)(lv + off);   // ds_read_b128
    const half8 bs = *(const half8*)(ls + off);   // ds_read_b128
    acc  = __builtin_amdgcn_mfma_f32_32x32x16_f16(a,  bv, acc,  0, 0, 0);
    accg = __builtin_amdgcn_mfma_f32_32x32x16_f16(ad, bs, accg, 0, 0, 0);
  }

  // ---- epilogue: D layout col=lane&31, row=(reg&3)+8*(reg>>2)+4*(lane>>5) ----
  const int y = y0 + w8;
#pragma unroll
  for (int reg = 0; reg < 16; ++reg) {
    const int o = (reg & 3) + 8 * (reg >> 2) + 4 * lh;
    out[(((size_t)(bb * COUT + o)) << 16) + (y << 8) + x0 + ln] =
        acc[reg] * accg[reg] + bias[o];
  }
}

extern "C" void kernel_launch(void* const* d_in, const int* in_sizes, int n_in,
                              void* d_out, int out_size, void* d_ws, size_t ws_size,
                              hipStream_t stream) {
  const float* x    = (const float*)d_in[0];
  const float* wgt  = (const float*)d_in[1];
  const float* dw   = (const float*)d_in[2];
  const float* bias = (const float*)d_in[3];
  float* out = (float*)d_out;

  _Float16* Apack = (_Float16*)d_ws;                    // 9216 f16
  _Float16* Adw   = Apack + 9216;                       // 9216 f16

  prep_pack<<<(18432 + 255) / 256, 256, 0, stream>>>(wgt, dw, Apack, Adw);
  dynconv<<<BATCH * (HH / TH) * (WW / TW), 512, 0, stream>>>(x, Apack, Adw, bias, out);
}